// Round 13
// baseline (440.581 us; speedup 1.0000x reference)
//
#include <hip/hip_runtime.h>
#include <math.h>

#define NN 100000
#define NE 1600000
#define ECAP 64      // ELL slots/node
#define GN 64        // nodes per gate-GEMM block
#define WSTR 296     // W^T row stride in ushorts
#define LSTR 104     // LDS bf16 row stride (96 + 8)

// binned build: 2D grid = edge-chunks x bin-groups
#define EPB 8192     // edges per chunk
#define NCHK 196     // ceil(NE/EPB)
#define BGRP 4       // bin-groups (reads edges 4x, 4x parallelism, same atomics)
#define BPG 98       // bins per group (4*98 >= 391)
#define BINB 256     // nodes per bin
#define NBINS 391    // ceil(NN/BINB)
#define BCAP 4736    // records per bin (mean 4092, +10 sigma)

typedef __attribute__((ext_vector_type(4))) float f32x4;
typedef __attribute__((ext_vector_type(8))) short s16x8;

__device__ __forceinline__ unsigned int bfbits(float v) {
  unsigned int b = __float_as_uint(v);
  b += 0x7fffu + ((b >> 16) & 1u);
  return b >> 16;
}
__device__ __forceinline__ float bflo(unsigned int v) { return __uint_as_float(v << 16); }
__device__ __forceinline__ float bfhi(unsigned int v) { return __uint_as_float(v & 0xffff0000u); }
__device__ __forceinline__ float bf1(unsigned short v) { return __uint_as_float((unsigned int)v << 16); }

// ---------------- binned graph build (bin-sliced) ----------------
__global__ __launch_bounds__(256) void k_binA(const int* __restrict__ src,
                                              const int* __restrict__ dst,
                                              const float* __restrict__ ew,
                                              int* __restrict__ gcur1,
                                              int* __restrict__ gcur2,
                                              int2* __restrict__ rec1,
                                              unsigned char* __restrict__ rec2) {
  __shared__ int h1[BPG], h2[BPG];
  int tid = threadIdx.x;
  int bg = blockIdx.x & (BGRP - 1);
  int chunk = blockIdx.x >> 2;
  int lo = bg * BPG;
  int hi = lo + BPG; if (hi > NBINS) hi = NBINS;
  for (int t = tid; t < BPG; t += 256) { h1[t] = 0; h2[t] = 0; }
  __syncthreads();
  int base = chunk * EPB;
  int end = base + EPB; if (end > NE) end = NE;
  for (int e = base + tid; e < end; e += 256) {
    int db = dst[e] >> 8, sb = src[e] >> 8;
    if (db >= lo && db < hi) atomicAdd(&h1[db - lo], 1);
    if (sb >= lo && sb < hi) atomicAdd(&h2[sb - lo], 1);
  }
  __syncthreads();
  for (int t = tid; t < hi - lo; t += 256) {
    int c1 = h1[t];
    h1[t] = (lo + t) * BCAP + (c1 ? atomicAdd(&gcur1[lo + t], c1) : 0);
    int c2 = h2[t];
    h2[t] = (lo + t) * BCAP + (c2 ? atomicAdd(&gcur2[lo + t], c2) : 0);
  }
  __syncthreads();
  for (int e = base + tid; e < end; e += 256) {
    int d = dst[e], s = src[e];
    int db = d >> 8, sb = s >> 8;
    if (db >= lo && db < hi) {
      int p1 = atomicAdd(&h1[db - lo], 1);
      rec1[p1] = make_int2(s | ((d & 255) << 20), __float_as_int(ew[e]));
    }
    if (sb >= lo && sb < hi) {
      int p2 = atomicAdd(&h2[sb - lo], 1);
      rec2[p2] = (unsigned char)(s & 255);
    }
  }
}

__global__ __launch_bounds__(256) void k_bdeg(const int* __restrict__ gcur2,
                                              const unsigned char* __restrict__ rec2,
                                              int* __restrict__ deg_out) {
  __shared__ int lc[BINB];
  int b = blockIdx.x, tid = threadIdx.x;
  lc[tid] = 0;
  __syncthreads();
  int cnt = gcur2[b];
  const unsigned char* rp = rec2 + (size_t)b * BCAP;
  for (int i = tid; i < cnt; i += 256) atomicAdd(&lc[rp[i]], 1);
  __syncthreads();
  int node = b * 256 + tid;
  if (node < NN) deg_out[node] = lc[tid];
}

// ELL fill with normalization applied here (deg_out ready).
__global__ __launch_bounds__(256) void k_bell(const int* __restrict__ gcur1,
                                              const int2* __restrict__ rec1,
                                              const int* __restrict__ deg_out,
                                              int2* __restrict__ ell,
                                              int* __restrict__ cursor) {
  __shared__ int lc[BINB];
  int b = blockIdx.x, tid = threadIdx.x;
  lc[tid] = 0;
  __syncthreads();
  int cnt = gcur1[b];
  const int2* rp = rec1 + (size_t)b * BCAP;
  for (int i = tid; i < cnt; i += 256) {
    int2 r = rp[i];
    int s = r.x & 0xFFFFF;
    int dl = (r.x >> 20) & 255;
    float w = __int_as_float(r.y) / fmaxf((float)deg_out[s], 1.0f);
    int p = atomicAdd(&lc[dl], 1);
    if (p < ECAP)
      ell[(size_t)(b * 256 + dl) * ECAP + p] = make_int2(s, __float_as_int(w));
  }
  __syncthreads();
  int node = b * 256 + tid;
  if (node < NN) cursor[node] = lc[tid];
}

// ---------------- xh0 = bf16 concat(x,h) ----------------
__global__ __launch_bounds__(256) void k_xh0(const float* __restrict__ x,
                                             const float* __restrict__ h,
                                             unsigned int* __restrict__ xh0) {
  int idx = blockIdx.x * 256 + threadIdx.x;
  if (idx >= NN * 48) return;
  int n = idx / 48, c = idx - n * 48;
  float v0, v1;
  if (c < 16) {
    v0 = x[(size_t)n * 32 + 2 * c];
    v1 = x[(size_t)n * 32 + 2 * c + 1];
  } else {
    v0 = h[(size_t)n * 64 + 2 * (c - 16)];
    v1 = h[(size_t)n * 64 + 2 * (c - 16) + 1];
  }
  xh0[idx] = bfbits(v0) | (bfbits(v1) << 16);
}

// ---------------- W prep ----------------
__global__ __launch_bounds__(256) void k_wprep(const float* __restrict__ Wr,
                                               const float* __restrict__ Wz,
                                               const float* __restrict__ Wc,
                                               unsigned short* __restrict__ wt_rz,
                                               unsigned short* __restrict__ wt_c) {
  int idx = blockIdx.x * 256 + threadIdx.x;
  if (idx >= 192 * 36) return;
  int col = idx % 192;
  int k0 = (idx / 192) * 8;
  unsigned int packed[4];
#pragma unroll
  for (int p = 0; p < 4; ++p) {
    unsigned int lo, hi;
#pragma unroll
    for (int e = 0; e < 2; ++e) {
      int k = k0 + p * 2 + e;
      int t = k / 96, kl = k - t * 96;
      float v;
      if (col < 64) v = Wr[t * 6144 + kl * 64 + col];
      else if (col < 128) v = Wz[t * 6144 + kl * 64 + (col - 64)];
      else v = Wc[t * 6144 + kl * 64 + (col - 128)];
      if (e == 0) lo = bfbits(v); else hi = bfbits(v);
    }
    packed[p] = lo | (hi << 16);
  }
  unsigned short* dstp = (col < 128) ? (wt_rz + col * WSTR + k0)
                                     : (wt_c + (col - 128) * WSTR + k0);
  *reinterpret_cast<uint4*>(dstp) =
      make_uint4(packed[0], packed[1], packed[2], packed[3]);
}

// ---------------- propagation: half-wave per node, ELL, 4x unrolled ----------
// ELL records streamed non-temporally (read once); outputs stored NT (not
// re-read this pass) -> keep L2 capacity for the gather rows.
__device__ __forceinline__ int2 nt_rec(const int2* p) {
  long long v = __builtin_nontemporal_load(reinterpret_cast<const long long*>(p));
  return make_int2((int)(v & 0xffffffffll), (int)(v >> 32));
}

__global__ __launch_bounds__(256) void k_prop96e(const uint2* __restrict__ in,
                                                 uint2* __restrict__ out,
                                                 const int* __restrict__ cnt_arr,
                                                 const int2* __restrict__ ell) {
  int hw = (blockIdx.x * 256 + threadIdx.x) >> 5;
  int lane = threadIdx.x & 31;
  if (hw >= NN) return;
  int cnt = cnt_arr[hw];
  if (cnt > ECAP) cnt = ECAP;
  const int2* ep = ell + (size_t)hw * ECAP;
  bool act = lane < 24;
  float a0 = 0.f, a1 = 0.f, a2 = 0.f, a3 = 0.f;
  float b0 = 0.f, b1 = 0.f, b2 = 0.f, b3 = 0.f;
  int i = 0;
  for (; i + 4 <= cnt; i += 4) {
    int2 e0 = nt_rec(ep + i), e1 = nt_rec(ep + i + 1);
    int2 e2 = nt_rec(ep + i + 2), e3 = nt_rec(ep + i + 3);
    if (act) {
      uint2 v0 = in[(size_t)e0.x * 24 + lane];
      uint2 v1 = in[(size_t)e1.x * 24 + lane];
      uint2 v2 = in[(size_t)e2.x * 24 + lane];
      uint2 v3 = in[(size_t)e3.x * 24 + lane];
      float w0 = __int_as_float(e0.y), w1 = __int_as_float(e1.y);
      float w2 = __int_as_float(e2.y), w3 = __int_as_float(e3.y);
      a0 = fmaf(w0, bflo(v0.x), a0); a1 = fmaf(w0, bfhi(v0.x), a1);
      a2 = fmaf(w0, bflo(v0.y), a2); a3 = fmaf(w0, bfhi(v0.y), a3);
      b0 = fmaf(w1, bflo(v1.x), b0); b1 = fmaf(w1, bfhi(v1.x), b1);
      b2 = fmaf(w1, bflo(v1.y), b2); b3 = fmaf(w1, bfhi(v1.y), b3);
      a0 = fmaf(w2, bflo(v2.x), a0); a1 = fmaf(w2, bfhi(v2.x), a1);
      a2 = fmaf(w2, bflo(v2.y), a2); a3 = fmaf(w2, bfhi(v2.y), a3);
      b0 = fmaf(w3, bflo(v3.x), b0); b1 = fmaf(w3, bfhi(v3.x), b1);
      b2 = fmaf(w3, bflo(v3.y), b2); b3 = fmaf(w3, bfhi(v3.y), b3);
    }
  }
  for (; i < cnt; ++i) {
    int2 e = nt_rec(ep + i);
    if (act) {
      uint2 v = in[(size_t)e.x * 24 + lane];
      float w = __int_as_float(e.y);
      a0 = fmaf(w, bflo(v.x), a0); a1 = fmaf(w, bfhi(v.x), a1);
      a2 = fmaf(w, bflo(v.y), a2); a3 = fmaf(w, bfhi(v.y), a3);
    }
  }
  if (act) {
    unsigned long long o =
        (unsigned long long)(bfbits(a0 + b0) | (bfbits(a1 + b1) << 16)) |
        ((unsigned long long)(bfbits(a2 + b2) | (bfbits(a3 + b3) << 16)) << 32);
    __builtin_nontemporal_store(o,
        reinterpret_cast<unsigned long long*>(out + (size_t)hw * 24 + lane));
  }
}

__global__ __launch_bounds__(256) void k_prop64e(const unsigned int* __restrict__ in,
                                                 unsigned int* __restrict__ out,
                                                 const int* __restrict__ cnt_arr,
                                                 const int2* __restrict__ ell) {
  int hw = (blockIdx.x * 256 + threadIdx.x) >> 5;
  int lane = threadIdx.x & 31;
  if (hw >= NN) return;
  int cnt = cnt_arr[hw];
  if (cnt > ECAP) cnt = ECAP;
  const int2* ep = ell + (size_t)hw * ECAP;
  float a0 = 0.f, a1 = 0.f, b0 = 0.f, b1 = 0.f;
  int i = 0;
  for (; i + 4 <= cnt; i += 4) {
    int2 e0 = nt_rec(ep + i), e1 = nt_rec(ep + i + 1);
    int2 e2 = nt_rec(ep + i + 2), e3 = nt_rec(ep + i + 3);
    unsigned int v0 = in[(size_t)e0.x * 32 + lane];
    unsigned int v1 = in[(size_t)e1.x * 32 + lane];
    unsigned int v2 = in[(size_t)e2.x * 32 + lane];
    unsigned int v3 = in[(size_t)e3.x * 32 + lane];
    float w0 = __int_as_float(e0.y), w1 = __int_as_float(e1.y);
    float w2 = __int_as_float(e2.y), w3 = __int_as_float(e3.y);
    a0 = fmaf(w0, bflo(v0), a0); a1 = fmaf(w0, bfhi(v0), a1);
    b0 = fmaf(w1, bflo(v1), b0); b1 = fmaf(w1, bfhi(v1), b1);
    a0 = fmaf(w2, bflo(v2), a0); a1 = fmaf(w2, bfhi(v2), a1);
    b0 = fmaf(w3, bflo(v3), b0); b1 = fmaf(w3, bfhi(v3), b1);
  }
  for (; i < cnt; ++i) {
    int2 e = nt_rec(ep + i);
    unsigned int v = in[(size_t)e.x * 32 + lane];
    float w = __int_as_float(e.y);
    a0 = fmaf(w, bflo(v), a0); a1 = fmaf(w, bfhi(v), a1);
  }
  __builtin_nontemporal_store(bfbits(a0 + b0) | (bfbits(a1 + b1) << 16),
                              out + (size_t)hw * 32 + lane);
}

// ---------------- gate staging (plain bf16 copies) ----------------
__device__ __forceinline__ void stage_copy96(unsigned short* sA, int nb0,
                                             const unsigned short* __restrict__ src) {
  for (int i = threadIdx.x; i < GN * 12; i += 256) {
    int n = i / 12, ch = i % 12;
    int g = nb0 + n;
    uint4 v = make_uint4(0, 0, 0, 0);
    if (g < NN) v = *reinterpret_cast<const uint4*>(src + (size_t)g * 96 + ch * 8);
    *reinterpret_cast<uint4*>(&sA[n * LSTR + ch * 8]) = v;
  }
}

__device__ __forceinline__ void stage_bfbf(unsigned short* sA, int nb0,
                                           const unsigned short* __restrict__ srcA,
                                           const unsigned short* __restrict__ srcB) {
  for (int i = threadIdx.x; i < GN * 12; i += 256) {
    int n = i / 12, ch = i % 12;
    int g = nb0 + n;
    uint4 v = make_uint4(0, 0, 0, 0);
    if (g < NN) {
      if (ch < 4) v = *reinterpret_cast<const uint4*>(srcA + (size_t)g * 96 + ch * 8);
      else v = *reinterpret_cast<const uint4*>(srcB + (size_t)g * 64 + (ch - 4) * 8);
    }
    *reinterpret_cast<uint4*>(&sA[n * LSTR + ch * 8]) = v;
  }
}

// ---------------- gates: bf16 MFMA GEMM, W from global (L2) ----------------
__global__ __launch_bounds__(256) void k_rz(const unsigned short* __restrict__ xh0,
                                            const unsigned short* __restrict__ xh1,
                                            const unsigned short* __restrict__ xh2,
                                            const unsigned short* __restrict__ wt_rz,
                                            const float* __restrict__ br,
                                            const float* __restrict__ bz,
                                            unsigned short* __restrict__ rh,
                                            unsigned short* __restrict__ zbb) {
  __shared__ alignas(16) unsigned short sA[GN * LSTR];
  int tid = threadIdx.x;
  int nb0 = blockIdx.x * GN;
  int wv = tid >> 6, l = tid & 63;
  int l15 = l & 15, lg = l >> 4;
  int n0 = wv * 32;

  f32x4 acc[4][2];
#pragma unroll
  for (int nt = 0; nt < 2; ++nt) {
    int colc = n0 + nt * 16 + l15;
    float bias = (colc < 64) ? br[colc] : bz[colc - 64];
#pragma unroll
    for (int mt = 0; mt < 4; ++mt) acc[mt][nt] = {bias, bias, bias, bias};
  }

  const unsigned short* w0p = wt_rz + (size_t)(n0 + l15) * WSTR + lg * 8;
  const unsigned short* w1p = wt_rz + (size_t)(n0 + 16 + l15) * WSTR + lg * 8;

#pragma unroll
  for (int t = 0; t < 3; ++t) {
    if (t == 0) stage_copy96(sA, nb0, xh0);
    else if (t == 1) stage_copy96(sA, nb0, xh1);
    else stage_copy96(sA, nb0, xh2);
    __syncthreads();
#pragma unroll
    for (int ks = 0; ks < 3; ++ks) {
      int kb = ks * 32 + lg * 8;
      s16x8 bf0 = *reinterpret_cast<const s16x8*>(w0p + t * 96 + ks * 32);
      s16x8 bf1 = *reinterpret_cast<const s16x8*>(w1p + t * 96 + ks * 32);
#pragma unroll
      for (int mt = 0; mt < 4; ++mt) {
        s16x8 af = *reinterpret_cast<const s16x8*>(&sA[(mt * 16 + l15) * LSTR + kb]);
        acc[mt][0] = __builtin_amdgcn_mfma_f32_16x16x32_bf16(af, bf0, acc[mt][0], 0, 0, 0);
        acc[mt][1] = __builtin_amdgcn_mfma_f32_16x16x32_bf16(af, bf1, acc[mt][1], 0, 0, 0);
      }
    }
    __syncthreads();
  }

#pragma unroll
  for (int mt = 0; mt < 4; ++mt) {
#pragma unroll
    for (int nt = 0; nt < 2; ++nt) {
      int colc = n0 + nt * 16 + l15;
#pragma unroll
      for (int r = 0; r < 4; ++r) {
        int g = nb0 + mt * 16 + lg * 4 + r;
        if (g < NN) {
          float pre = acc[mt][nt][r];
          float sg = 1.f / (1.f + expf(-pre));
          if (colc < 64) {
            float hv = bf1(xh0[(size_t)g * 96 + 32 + colc]);
            rh[(size_t)g * 64 + colc] = (unsigned short)bfbits(sg * hv);
          } else {
            zbb[(size_t)g * 64 + (colc - 64)] = (unsigned short)bfbits(sg);
          }
        }
      }
    }
  }
}

__global__ __launch_bounds__(256) void k_c(const unsigned short* __restrict__ xh0,
                                           const unsigned short* __restrict__ rhf,
                                           const unsigned short* __restrict__ xh1,
                                           const unsigned short* __restrict__ xh2,
                                           const unsigned short* __restrict__ rh1,
                                           const unsigned short* __restrict__ rh2,
                                           const unsigned short* __restrict__ wt_c,
                                           const float* __restrict__ bc,
                                           const unsigned short* __restrict__ zbb,
                                           float* __restrict__ out) {
  __shared__ alignas(16) unsigned short sA[GN * LSTR];
  int tid = threadIdx.x;
  int nb0 = blockIdx.x * GN;
  int wv = tid >> 6, l = tid & 63;
  int l15 = l & 15, lg = l >> 4;
  int n0 = wv * 16;

  float bias = bc[n0 + l15];
  f32x4 acc[4];
#pragma unroll
  for (int mt = 0; mt < 4; ++mt) acc[mt] = {bias, bias, bias, bias};

  const unsigned short* wp = wt_c + (size_t)(n0 + l15) * WSTR + lg * 8;

#pragma unroll
  for (int t = 0; t < 3; ++t) {
    if (t == 0) stage_bfbf(sA, nb0, xh0, rhf);
    else if (t == 1) stage_bfbf(sA, nb0, xh1, rh1);
    else stage_bfbf(sA, nb0, xh2, rh2);
    __syncthreads();
#pragma unroll
    for (int ks = 0; ks < 3; ++ks) {
      int kb = ks * 32 + lg * 8;
      s16x8 bf0 = *reinterpret_cast<const s16x8*>(wp + t * 96 + ks * 32);
#pragma unroll
      for (int mt = 0; mt < 4; ++mt) {
        s16x8 af = *reinterpret_cast<const s16x8*>(&sA[(mt * 16 + l15) * LSTR + kb]);
        acc[mt] = __builtin_amdgcn_mfma_f32_16x16x32_bf16(af, bf0, acc[mt], 0, 0, 0);
      }
    }
    __syncthreads();
  }

  int colc = n0 + l15;
#pragma unroll
  for (int mt = 0; mt < 4; ++mt) {
#pragma unroll
    for (int r = 0; r < 4; ++r) {
      int g = nb0 + mt * 16 + lg * 4 + r;
      if (g < NN) {
        float cv = tanhf(acc[mt][r]);
        float z = bf1(zbb[(size_t)g * 64 + colc]);
        float hv = bf1(xh0[(size_t)g * 96 + 32 + colc]);
        out[(size_t)g * 64 + colc] = z * hv + (1.f - z) * cv;
      }
    }
  }
}

// ---------------- launch ----------------
extern "C" void kernel_launch(void* const* d_in, const int* in_sizes, int n_in,
                              void* d_out, int out_size, void* d_ws, size_t ws_size,
                              hipStream_t stream) {
  const float* x = (const float*)d_in[0];
  const float* h = (const float*)d_in[1];
  const int* eidx = (const int*)d_in[2];
  const float* ew = (const float*)d_in[3];
  const float* Wr = (const float*)d_in[4];
  const float* br = (const float*)d_in[5];
  const float* Wz = (const float*)d_in[6];
  const float* bz = (const float*)d_in[7];
  const float* Wc = (const float*)d_in[8];
  const float* bc = (const float*)d_in[9];
  const int* src = eidx;
  const int* dst = eidx + NE;
  float* out = (float*)d_out;

  int* ip = (int*)d_ws;
  int* gcur1 = ip;                          // 512
  int* gcur2 = ip + 512;                    // 512
  int* deg_out = ip + 1024;                 // NN
  int* cursor = deg_out + NN;               // NN
  int2* rec1 = (int2*)(cursor + NN);        // NBINS*BCAP int2
  unsigned char* rec2 = (unsigned char*)(rec1 + (size_t)NBINS * BCAP);  // NBINS*BCAP
  int2* ell = (int2*)(rec2 + ((size_t)NBINS * BCAP + 8) / 8 * 8);       // NN*ECAP
  unsigned short* zbb = (unsigned short*)(ell + (size_t)NN * ECAP);     // NN*64 bf16
  unsigned short* xh0 = zbb + (size_t)NN * 64;                          // NN*96 bf16
  unsigned short* xh1 = xh0 + (size_t)NN * 96;
  unsigned short* xh2 = xh1 + (size_t)NN * 96;
  unsigned short* rh  = xh2 + (size_t)NN * 96;   // NN*64 bf16
  unsigned short* rh1 = rh + (size_t)NN * 64;
  unsigned short* rh2 = rh1 + (size_t)NN * 64;
  unsigned short* wt_rz = rh2 + (size_t)NN * 64; // 128*WSTR
  unsigned short* wt_c = wt_rz + 128 * WSTR;     // 64*WSTR

  hipMemsetAsync(ip, 0, 1024 * sizeof(int), stream);

  dim3 blk(256);
  k_wprep<<<dim3((192 * 36 + 255) / 256), blk, 0, stream>>>(Wr, Wz, Wc, wt_rz, wt_c);
  k_binA<<<dim3(NCHK * BGRP), blk, 0, stream>>>(src, dst, ew, gcur1, gcur2, rec1, rec2);
  k_bdeg<<<dim3(NBINS), blk, 0, stream>>>(gcur2, rec2, deg_out);
  k_bell<<<dim3(NBINS), blk, 0, stream>>>(gcur1, rec1, deg_out, ell, cursor);
  k_xh0<<<dim3(NN * 48 / 256), blk, 0, stream>>>(x, h, (unsigned int*)xh0);

  k_prop96e<<<dim3(NN / 8), blk, 0, stream>>>((const uint2*)xh0, (uint2*)xh1,
                                              cursor, ell);
  k_prop96e<<<dim3(NN / 8), blk, 0, stream>>>((const uint2*)xh1, (uint2*)xh2,
                                              cursor, ell);
  k_rz<<<dim3((NN + GN - 1) / GN), blk, 0, stream>>>(xh0, xh1, xh2, wt_rz, br, bz, rh, zbb);
  k_prop64e<<<dim3(NN / 8), blk, 0, stream>>>((const unsigned int*)rh,
                                              (unsigned int*)rh1, cursor, ell);
  k_prop64e<<<dim3(NN / 8), blk, 0, stream>>>((const unsigned int*)rh1,
                                              (unsigned int*)rh2, cursor, ell);
  k_c<<<dim3((NN + GN - 1) / GN), blk, 0, stream>>>(xh0, rh, xh1, xh2, rh1, rh2,
                                                    wt_c, bc, zbb, out);
}

// Round 14
// 379.647 us; speedup vs baseline: 1.1605x; 1.1605x over previous
//
#include <hip/hip_runtime.h>
#include <math.h>

#define NN 100000
#define NE 1600000
#define ECAP 64      // ELL slots/node
#define GN 64        // nodes per gate-GEMM block
#define WSTR 296     // W^T row stride in ushorts
#define LSTR 104     // LDS bf16 row stride (96 + 8)

// binned build
#define EPB 4096     // edges per phase-A block
#define NBLKA 391    // ceil(NE/EPB)
#define BINB 256     // nodes per bin
#define NBINS 391    // ceil(NN/BINB)
#define BCAP 4736    // records per bin (mean 4092, +10 sigma)

typedef __attribute__((ext_vector_type(4))) float f32x4;
typedef __attribute__((ext_vector_type(8))) short s16x8;

__device__ __forceinline__ unsigned int bfbits(float v) {
  unsigned int b = __float_as_uint(v);
  b += 0x7fffu + ((b >> 16) & 1u);
  return b >> 16;
}
__device__ __forceinline__ float bflo(unsigned int v) { return __uint_as_float(v << 16); }
__device__ __forceinline__ float bfhi(unsigned int v) { return __uint_as_float(v & 0xffff0000u); }
__device__ __forceinline__ float bf1(unsigned short v) { return __uint_as_float((unsigned int)v << 16); }

// ---------------- binned graph build ----------------
__global__ __launch_bounds__(256) void k_binA(const int* __restrict__ src,
                                              const int* __restrict__ dst,
                                              const float* __restrict__ ew,
                                              int* __restrict__ gcur1,
                                              int* __restrict__ gcur2,
                                              int2* __restrict__ rec1,
                                              unsigned char* __restrict__ rec2) {
  __shared__ int h1[NBINS], h2[NBINS];
  int tid = threadIdx.x;
  for (int t = tid; t < NBINS; t += 256) { h1[t] = 0; h2[t] = 0; }
  __syncthreads();
  int base = blockIdx.x * EPB;
  int end = base + EPB; if (end > NE) end = NE;
  for (int e = base + tid; e < end; e += 256) {
    atomicAdd(&h1[dst[e] >> 8], 1);
    atomicAdd(&h2[src[e] >> 8], 1);
  }
  __syncthreads();
  for (int t = tid; t < NBINS; t += 256) {
    int c1 = h1[t];
    h1[t] = t * BCAP + (c1 ? atomicAdd(&gcur1[t], c1) : 0);
    int c2 = h2[t];
    h2[t] = t * BCAP + (c2 ? atomicAdd(&gcur2[t], c2) : 0);
  }
  __syncthreads();
  for (int e = base + tid; e < end; e += 256) {
    int d = dst[e], s = src[e];
    int p1 = atomicAdd(&h1[d >> 8], 1);
    rec1[p1] = make_int2(s | ((d & 255) << 20), __float_as_int(ew[e]));
    int p2 = atomicAdd(&h2[s >> 8], 1);
    rec2[p2] = (unsigned char)(s & 255);
  }
}

__global__ __launch_bounds__(256) void k_bdeg(const int* __restrict__ gcur2,
                                              const unsigned char* __restrict__ rec2,
                                              int* __restrict__ deg_out) {
  __shared__ int lc[BINB];
  int b = blockIdx.x, tid = threadIdx.x;
  lc[tid] = 0;
  __syncthreads();
  int cnt = gcur2[b];
  const unsigned char* rp = rec2 + (size_t)b * BCAP;
  for (int i = tid; i < cnt; i += 256) atomicAdd(&lc[rp[i]], 1);
  __syncthreads();
  int node = b * 256 + tid;
  if (node < NN) deg_out[node] = lc[tid];
}

// ELL fill with normalization applied here (deg_out ready).
__global__ __launch_bounds__(256) void k_bell(const int* __restrict__ gcur1,
                                              const int2* __restrict__ rec1,
                                              const int* __restrict__ deg_out,
                                              int2* __restrict__ ell,
                                              int* __restrict__ cursor) {
  __shared__ int lc[BINB];
  int b = blockIdx.x, tid = threadIdx.x;
  lc[tid] = 0;
  __syncthreads();
  int cnt = gcur1[b];
  const int2* rp = rec1 + (size_t)b * BCAP;
  for (int i = tid; i < cnt; i += 256) {
    int2 r = rp[i];
    int s = r.x & 0xFFFFF;
    int dl = (r.x >> 20) & 255;
    float w = __int_as_float(r.y) / fmaxf((float)deg_out[s], 1.0f);
    int p = atomicAdd(&lc[dl], 1);
    if (p < ECAP)
      ell[(size_t)(b * 256 + dl) * ECAP + p] = make_int2(s, __float_as_int(w));
  }
  __syncthreads();
  int node = b * 256 + tid;
  if (node < NN) cursor[node] = lc[tid];
}

// ---------------- xh0 = bf16 concat(x,h) ----------------
__global__ __launch_bounds__(256) void k_xh0(const float* __restrict__ x,
                                             const float* __restrict__ h,
                                             unsigned int* __restrict__ xh0) {
  int idx = blockIdx.x * 256 + threadIdx.x;
  if (idx >= NN * 48) return;
  int n = idx / 48, c = idx - n * 48;
  float v0, v1;
  if (c < 16) {
    v0 = x[(size_t)n * 32 + 2 * c];
    v1 = x[(size_t)n * 32 + 2 * c + 1];
  } else {
    v0 = h[(size_t)n * 64 + 2 * (c - 16)];
    v1 = h[(size_t)n * 64 + 2 * (c - 16) + 1];
  }
  xh0[idx] = bfbits(v0) | (bfbits(v1) << 16);
}

// ---------------- W prep ----------------
__global__ __launch_bounds__(256) void k_wprep(const float* __restrict__ Wr,
                                               const float* __restrict__ Wz,
                                               const float* __restrict__ Wc,
                                               unsigned short* __restrict__ wt_rz,
                                               unsigned short* __restrict__ wt_c) {
  int idx = blockIdx.x * 256 + threadIdx.x;
  if (idx >= 192 * 36) return;
  int col = idx % 192;
  int k0 = (idx / 192) * 8;
  unsigned int packed[4];
#pragma unroll
  for (int p = 0; p < 4; ++p) {
    unsigned int lo, hi;
#pragma unroll
    for (int e = 0; e < 2; ++e) {
      int k = k0 + p * 2 + e;
      int t = k / 96, kl = k - t * 96;
      float v;
      if (col < 64) v = Wr[t * 6144 + kl * 64 + col];
      else if (col < 128) v = Wz[t * 6144 + kl * 64 + (col - 64)];
      else v = Wc[t * 6144 + kl * 64 + (col - 128)];
      if (e == 0) lo = bfbits(v); else hi = bfbits(v);
    }
    packed[p] = lo | (hi << 16);
  }
  unsigned short* dstp = (col < 128) ? (wt_rz + col * WSTR + k0)
                                     : (wt_c + (col - 128) * WSTR + k0);
  *reinterpret_cast<uint4*>(dstp) =
      make_uint4(packed[0], packed[1], packed[2], packed[3]);
}

// ---------------- propagation: half-wave per node, ELL, 8x unrolled ----------
__global__ __launch_bounds__(256) void k_prop96e(const uint2* __restrict__ in,
                                                 uint2* __restrict__ out,
                                                 const int* __restrict__ cnt_arr,
                                                 const int2* __restrict__ ell) {
  int hw = (blockIdx.x * 256 + threadIdx.x) >> 5;
  int lane = threadIdx.x & 31;
  if (hw >= NN) return;
  int cnt = cnt_arr[hw];
  if (cnt > ECAP) cnt = ECAP;
  const int2* ep = ell + (size_t)hw * ECAP;
  bool act = lane < 24;
  float a0 = 0.f, a1 = 0.f, a2 = 0.f, a3 = 0.f;
  float b0 = 0.f, b1 = 0.f, b2 = 0.f, b3 = 0.f;
  int i = 0;
  for (; i + 8 <= cnt; i += 8) {
    int2 e0 = ep[i], e1 = ep[i + 1], e2 = ep[i + 2], e3 = ep[i + 3];
    int2 e4 = ep[i + 4], e5 = ep[i + 5], e6 = ep[i + 6], e7 = ep[i + 7];
    if (act) {
      uint2 v0 = in[(size_t)e0.x * 24 + lane];
      uint2 v1 = in[(size_t)e1.x * 24 + lane];
      uint2 v2 = in[(size_t)e2.x * 24 + lane];
      uint2 v3 = in[(size_t)e3.x * 24 + lane];
      uint2 v4 = in[(size_t)e4.x * 24 + lane];
      uint2 v5 = in[(size_t)e5.x * 24 + lane];
      uint2 v6 = in[(size_t)e6.x * 24 + lane];
      uint2 v7 = in[(size_t)e7.x * 24 + lane];
      float w0 = __int_as_float(e0.y), w1 = __int_as_float(e1.y);
      float w2 = __int_as_float(e2.y), w3 = __int_as_float(e3.y);
      float w4 = __int_as_float(e4.y), w5 = __int_as_float(e5.y);
      float w6 = __int_as_float(e6.y), w7 = __int_as_float(e7.y);
      a0 = fmaf(w0, bflo(v0.x), a0); a1 = fmaf(w0, bfhi(v0.x), a1);
      a2 = fmaf(w0, bflo(v0.y), a2); a3 = fmaf(w0, bfhi(v0.y), a3);
      b0 = fmaf(w1, bflo(v1.x), b0); b1 = fmaf(w1, bfhi(v1.x), b1);
      b2 = fmaf(w1, bflo(v1.y), b2); b3 = fmaf(w1, bfhi(v1.y), b3);
      a0 = fmaf(w2, bflo(v2.x), a0); a1 = fmaf(w2, bfhi(v2.x), a1);
      a2 = fmaf(w2, bflo(v2.y), a2); a3 = fmaf(w2, bfhi(v2.y), a3);
      b0 = fmaf(w3, bflo(v3.x), b0); b1 = fmaf(w3, bfhi(v3.x), b1);
      b2 = fmaf(w3, bflo(v3.y), b2); b3 = fmaf(w3, bfhi(v3.y), b3);
      a0 = fmaf(w4, bflo(v4.x), a0); a1 = fmaf(w4, bfhi(v4.x), a1);
      a2 = fmaf(w4, bflo(v4.y), a2); a3 = fmaf(w4, bfhi(v4.y), a3);
      b0 = fmaf(w5, bflo(v5.x), b0); b1 = fmaf(w5, bfhi(v5.x), b1);
      b2 = fmaf(w5, bflo(v5.y), b2); b3 = fmaf(w5, bfhi(v5.y), b3);
      a0 = fmaf(w6, bflo(v6.x), a0); a1 = fmaf(w6, bfhi(v6.x), a1);
      a2 = fmaf(w6, bflo(v6.y), a2); a3 = fmaf(w6, bfhi(v6.y), a3);
      b0 = fmaf(w7, bflo(v7.x), b0); b1 = fmaf(w7, bfhi(v7.x), b1);
      b2 = fmaf(w7, bflo(v7.y), b2); b3 = fmaf(w7, bfhi(v7.y), b3);
    }
  }
  for (; i + 4 <= cnt; i += 4) {
    int2 e0 = ep[i], e1 = ep[i + 1], e2 = ep[i + 2], e3 = ep[i + 3];
    if (act) {
      uint2 v0 = in[(size_t)e0.x * 24 + lane];
      uint2 v1 = in[(size_t)e1.x * 24 + lane];
      uint2 v2 = in[(size_t)e2.x * 24 + lane];
      uint2 v3 = in[(size_t)e3.x * 24 + lane];
      float w0 = __int_as_float(e0.y), w1 = __int_as_float(e1.y);
      float w2 = __int_as_float(e2.y), w3 = __int_as_float(e3.y);
      a0 = fmaf(w0, bflo(v0.x), a0); a1 = fmaf(w0, bfhi(v0.x), a1);
      a2 = fmaf(w0, bflo(v0.y), a2); a3 = fmaf(w0, bfhi(v0.y), a3);
      b0 = fmaf(w1, bflo(v1.x), b0); b1 = fmaf(w1, bfhi(v1.x), b1);
      b2 = fmaf(w1, bflo(v1.y), b2); b3 = fmaf(w1, bfhi(v1.y), b3);
      a0 = fmaf(w2, bflo(v2.x), a0); a1 = fmaf(w2, bfhi(v2.x), a1);
      a2 = fmaf(w2, bflo(v2.y), a2); a3 = fmaf(w2, bfhi(v2.y), a3);
      b0 = fmaf(w3, bflo(v3.x), b0); b1 = fmaf(w3, bfhi(v3.x), b1);
      b2 = fmaf(w3, bflo(v3.y), b2); b3 = fmaf(w3, bfhi(v3.y), b3);
    }
  }
  for (; i < cnt; ++i) {
    int2 e = ep[i];
    if (act) {
      uint2 v = in[(size_t)e.x * 24 + lane];
      float w = __int_as_float(e.y);
      a0 = fmaf(w, bflo(v.x), a0); a1 = fmaf(w, bfhi(v.x), a1);
      a2 = fmaf(w, bflo(v.y), a2); a3 = fmaf(w, bfhi(v.y), a3);
    }
  }
  if (act) {
    uint2 o;
    o.x = bfbits(a0 + b0) | (bfbits(a1 + b1) << 16);
    o.y = bfbits(a2 + b2) | (bfbits(a3 + b3) << 16);
    out[(size_t)hw * 24 + lane] = o;
  }
}

__global__ __launch_bounds__(256) void k_prop64e(const unsigned int* __restrict__ in,
                                                 unsigned int* __restrict__ out,
                                                 const int* __restrict__ cnt_arr,
                                                 const int2* __restrict__ ell) {
  int hw = (blockIdx.x * 256 + threadIdx.x) >> 5;
  int lane = threadIdx.x & 31;
  if (hw >= NN) return;
  int cnt = cnt_arr[hw];
  if (cnt > ECAP) cnt = ECAP;
  const int2* ep = ell + (size_t)hw * ECAP;
  float a0 = 0.f, a1 = 0.f, b0 = 0.f, b1 = 0.f;
  int i = 0;
  for (; i + 8 <= cnt; i += 8) {
    int2 e0 = ep[i], e1 = ep[i + 1], e2 = ep[i + 2], e3 = ep[i + 3];
    int2 e4 = ep[i + 4], e5 = ep[i + 5], e6 = ep[i + 6], e7 = ep[i + 7];
    unsigned int v0 = in[(size_t)e0.x * 32 + lane];
    unsigned int v1 = in[(size_t)e1.x * 32 + lane];
    unsigned int v2 = in[(size_t)e2.x * 32 + lane];
    unsigned int v3 = in[(size_t)e3.x * 32 + lane];
    unsigned int v4 = in[(size_t)e4.x * 32 + lane];
    unsigned int v5 = in[(size_t)e5.x * 32 + lane];
    unsigned int v6 = in[(size_t)e6.x * 32 + lane];
    unsigned int v7 = in[(size_t)e7.x * 32 + lane];
    float w0 = __int_as_float(e0.y), w1 = __int_as_float(e1.y);
    float w2 = __int_as_float(e2.y), w3 = __int_as_float(e3.y);
    float w4 = __int_as_float(e4.y), w5 = __int_as_float(e5.y);
    float w6 = __int_as_float(e6.y), w7 = __int_as_float(e7.y);
    a0 = fmaf(w0, bflo(v0), a0); a1 = fmaf(w0, bfhi(v0), a1);
    b0 = fmaf(w1, bflo(v1), b0); b1 = fmaf(w1, bfhi(v1), b1);
    a0 = fmaf(w2, bflo(v2), a0); a1 = fmaf(w2, bfhi(v2), a1);
    b0 = fmaf(w3, bflo(v3), b0); b1 = fmaf(w3, bfhi(v3), b1);
    a0 = fmaf(w4, bflo(v4), a0); a1 = fmaf(w4, bfhi(v4), a1);
    b0 = fmaf(w5, bflo(v5), b0); b1 = fmaf(w5, bfhi(v5), b1);
    a0 = fmaf(w6, bflo(v6), a0); a1 = fmaf(w6, bfhi(v6), a1);
    b0 = fmaf(w7, bflo(v7), b0); b1 = fmaf(w7, bfhi(v7), b1);
  }
  for (; i + 4 <= cnt; i += 4) {
    int2 e0 = ep[i], e1 = ep[i + 1], e2 = ep[i + 2], e3 = ep[i + 3];
    unsigned int v0 = in[(size_t)e0.x * 32 + lane];
    unsigned int v1 = in[(size_t)e1.x * 32 + lane];
    unsigned int v2 = in[(size_t)e2.x * 32 + lane];
    unsigned int v3 = in[(size_t)e3.x * 32 + lane];
    float w0 = __int_as_float(e0.y), w1 = __int_as_float(e1.y);
    float w2 = __int_as_float(e2.y), w3 = __int_as_float(e3.y);
    a0 = fmaf(w0, bflo(v0), a0); a1 = fmaf(w0, bfhi(v0), a1);
    b0 = fmaf(w1, bflo(v1), b0); b1 = fmaf(w1, bfhi(v1), b1);
    a0 = fmaf(w2, bflo(v2), a0); a1 = fmaf(w2, bfhi(v2), a1);
    b0 = fmaf(w3, bflo(v3), b0); b1 = fmaf(w3, bfhi(v3), b1);
  }
  for (; i < cnt; ++i) {
    int2 e = ep[i];
    unsigned int v = in[(size_t)e.x * 32 + lane];
    float w = __int_as_float(e.y);
    a0 = fmaf(w, bflo(v), a0); a1 = fmaf(w, bfhi(v), a1);
  }
  out[(size_t)hw * 32 + lane] = bfbits(a0 + b0) | (bfbits(a1 + b1) << 16);
}

// ---------------- gate staging (plain bf16 copies) ----------------
__device__ __forceinline__ void stage_copy96(unsigned short* sA, int nb0,
                                             const unsigned short* __restrict__ src) {
  for (int i = threadIdx.x; i < GN * 12; i += 256) {
    int n = i / 12, ch = i % 12;
    int g = nb0 + n;
    uint4 v = make_uint4(0, 0, 0, 0);
    if (g < NN) v = *reinterpret_cast<const uint4*>(src + (size_t)g * 96 + ch * 8);
    *reinterpret_cast<uint4*>(&sA[n * LSTR + ch * 8]) = v;
  }
}

__device__ __forceinline__ void stage_bfbf(unsigned short* sA, int nb0,
                                           const unsigned short* __restrict__ srcA,
                                           const unsigned short* __restrict__ srcB) {
  for (int i = threadIdx.x; i < GN * 12; i += 256) {
    int n = i / 12, ch = i % 12;
    int g = nb0 + n;
    uint4 v = make_uint4(0, 0, 0, 0);
    if (g < NN) {
      if (ch < 4) v = *reinterpret_cast<const uint4*>(srcA + (size_t)g * 96 + ch * 8);
      else v = *reinterpret_cast<const uint4*>(srcB + (size_t)g * 64 + (ch - 4) * 8);
    }
    *reinterpret_cast<uint4*>(&sA[n * LSTR + ch * 8]) = v;
  }
}

// ---------------- gates: bf16 MFMA GEMM, W from global (L2) ----------------
__global__ __launch_bounds__(256) void k_rz(const unsigned short* __restrict__ xh0,
                                            const unsigned short* __restrict__ xh1,
                                            const unsigned short* __restrict__ xh2,
                                            const unsigned short* __restrict__ wt_rz,
                                            const float* __restrict__ br,
                                            const float* __restrict__ bz,
                                            unsigned short* __restrict__ rh,
                                            unsigned short* __restrict__ zbb) {
  __shared__ alignas(16) unsigned short sA[GN * LSTR];
  int tid = threadIdx.x;
  int nb0 = blockIdx.x * GN;
  int wv = tid >> 6, l = tid & 63;
  int l15 = l & 15, lg = l >> 4;
  int n0 = wv * 32;

  f32x4 acc[4][2];
#pragma unroll
  for (int nt = 0; nt < 2; ++nt) {
    int colc = n0 + nt * 16 + l15;
    float bias = (colc < 64) ? br[colc] : bz[colc - 64];
#pragma unroll
    for (int mt = 0; mt < 4; ++mt) acc[mt][nt] = {bias, bias, bias, bias};
  }

  const unsigned short* w0p = wt_rz + (size_t)(n0 + l15) * WSTR + lg * 8;
  const unsigned short* w1p = wt_rz + (size_t)(n0 + 16 + l15) * WSTR + lg * 8;

#pragma unroll
  for (int t = 0; t < 3; ++t) {
    if (t == 0) stage_copy96(sA, nb0, xh0);
    else if (t == 1) stage_copy96(sA, nb0, xh1);
    else stage_copy96(sA, nb0, xh2);
    __syncthreads();
#pragma unroll
    for (int ks = 0; ks < 3; ++ks) {
      int kb = ks * 32 + lg * 8;
      s16x8 bf0 = *reinterpret_cast<const s16x8*>(w0p + t * 96 + ks * 32);
      s16x8 bf1 = *reinterpret_cast<const s16x8*>(w1p + t * 96 + ks * 32);
#pragma unroll
      for (int mt = 0; mt < 4; ++mt) {
        s16x8 af = *reinterpret_cast<const s16x8*>(&sA[(mt * 16 + l15) * LSTR + kb]);
        acc[mt][0] = __builtin_amdgcn_mfma_f32_16x16x32_bf16(af, bf0, acc[mt][0], 0, 0, 0);
        acc[mt][1] = __builtin_amdgcn_mfma_f32_16x16x32_bf16(af, bf1, acc[mt][1], 0, 0, 0);
      }
    }
    __syncthreads();
  }

#pragma unroll
  for (int mt = 0; mt < 4; ++mt) {
#pragma unroll
    for (int nt = 0; nt < 2; ++nt) {
      int colc = n0 + nt * 16 + l15;
#pragma unroll
      for (int r = 0; r < 4; ++r) {
        int g = nb0 + mt * 16 + lg * 4 + r;
        if (g < NN) {
          float pre = acc[mt][nt][r];
          float sg = 1.f / (1.f + expf(-pre));
          if (colc < 64) {
            float hv = bf1(xh0[(size_t)g * 96 + 32 + colc]);
            rh[(size_t)g * 64 + colc] = (unsigned short)bfbits(sg * hv);
          } else {
            zbb[(size_t)g * 64 + (colc - 64)] = (unsigned short)bfbits(sg);
          }
        }
      }
    }
  }
}

__global__ __launch_bounds__(256) void k_c(const unsigned short* __restrict__ xh0,
                                           const unsigned short* __restrict__ rhf,
                                           const unsigned short* __restrict__ xh1,
                                           const unsigned short* __restrict__ xh2,
                                           const unsigned short* __restrict__ rh1,
                                           const unsigned short* __restrict__ rh2,
                                           const unsigned short* __restrict__ wt_c,
                                           const float* __restrict__ bc,
                                           const unsigned short* __restrict__ zbb,
                                           float* __restrict__ out) {
  __shared__ alignas(16) unsigned short sA[GN * LSTR];
  int tid = threadIdx.x;
  int nb0 = blockIdx.x * GN;
  int wv = tid >> 6, l = tid & 63;
  int l15 = l & 15, lg = l >> 4;
  int n0 = wv * 16;

  float bias = bc[n0 + l15];
  f32x4 acc[4];
#pragma unroll
  for (int mt = 0; mt < 4; ++mt) acc[mt] = {bias, bias, bias, bias};

  const unsigned short* wp = wt_c + (size_t)(n0 + l15) * WSTR + lg * 8;

#pragma unroll
  for (int t = 0; t < 3; ++t) {
    if (t == 0) stage_bfbf(sA, nb0, xh0, rhf);
    else if (t == 1) stage_bfbf(sA, nb0, xh1, rh1);
    else stage_bfbf(sA, nb0, xh2, rh2);
    __syncthreads();
#pragma unroll
    for (int ks = 0; ks < 3; ++ks) {
      int kb = ks * 32 + lg * 8;
      s16x8 bf0 = *reinterpret_cast<const s16x8*>(wp + t * 96 + ks * 32);
#pragma unroll
      for (int mt = 0; mt < 4; ++mt) {
        s16x8 af = *reinterpret_cast<const s16x8*>(&sA[(mt * 16 + l15) * LSTR + kb]);
        acc[mt] = __builtin_amdgcn_mfma_f32_16x16x32_bf16(af, bf0, acc[mt], 0, 0, 0);
      }
    }
    __syncthreads();
  }

  int colc = n0 + l15;
#pragma unroll
  for (int mt = 0; mt < 4; ++mt) {
#pragma unroll
    for (int r = 0; r < 4; ++r) {
      int g = nb0 + mt * 16 + lg * 4 + r;
      if (g < NN) {
        float cv = tanhf(acc[mt][r]);
        float z = bf1(zbb[(size_t)g * 64 + colc]);
        float hv = bf1(xh0[(size_t)g * 96 + 32 + colc]);
        out[(size_t)g * 64 + colc] = z * hv + (1.f - z) * cv;
      }
    }
  }
}

// ---------------- launch ----------------
extern "C" void kernel_launch(void* const* d_in, const int* in_sizes, int n_in,
                              void* d_out, int out_size, void* d_ws, size_t ws_size,
                              hipStream_t stream) {
  const float* x = (const float*)d_in[0];
  const float* h = (const float*)d_in[1];
  const int* eidx = (const int*)d_in[2];
  const float* ew = (const float*)d_in[3];
  const float* Wr = (const float*)d_in[4];
  const float* br = (const float*)d_in[5];
  const float* Wz = (const float*)d_in[6];
  const float* bz = (const float*)d_in[7];
  const float* Wc = (const float*)d_in[8];
  const float* bc = (const float*)d_in[9];
  const int* src = eidx;
  const int* dst = eidx + NE;
  float* out = (float*)d_out;

  int* ip = (int*)d_ws;
  int* gcur1 = ip;                          // 512
  int* gcur2 = ip + 512;                    // 512
  int* deg_out = ip + 1024;                 // NN
  int* cursor = deg_out + NN;               // NN
  int2* rec1 = (int2*)(cursor + NN);        // NBINS*BCAP int2
  unsigned char* rec2 = (unsigned char*)(rec1 + (size_t)NBINS * BCAP);  // NBINS*BCAP
  int2* ell = (int2*)(rec2 + ((size_t)NBINS * BCAP + 8) / 8 * 8);       // NN*ECAP
  unsigned short* zbb = (unsigned short*)(ell + (size_t)NN * ECAP);     // NN*64 bf16
  unsigned short* xh0 = zbb + (size_t)NN * 64;                          // NN*96 bf16
  unsigned short* xh1 = xh0 + (size_t)NN * 96;
  unsigned short* xh2 = xh1 + (size_t)NN * 96;
  unsigned short* rh  = xh2 + (size_t)NN * 96;   // NN*64 bf16
  unsigned short* rh1 = rh + (size_t)NN * 64;
  unsigned short* rh2 = rh1 + (size_t)NN * 64;
  unsigned short* wt_rz = rh2 + (size_t)NN * 64; // 128*WSTR
  unsigned short* wt_c = wt_rz + 128 * WSTR;     // 64*WSTR

  hipMemsetAsync(ip, 0, 1024 * sizeof(int), stream);

  dim3 blk(256);
  k_wprep<<<dim3((192 * 36 + 255) / 256), blk, 0, stream>>>(Wr, Wz, Wc, wt_rz, wt_c);
  k_binA<<<dim3(NBLKA), blk, 0, stream>>>(src, dst, ew, gcur1, gcur2, rec1, rec2);
  k_bdeg<<<dim3(NBINS), blk, 0, stream>>>(gcur2, rec2, deg_out);
  k_bell<<<dim3(NBINS), blk, 0, stream>>>(gcur1, rec1, deg_out, ell, cursor);
  k_xh0<<<dim3(NN * 48 / 256), blk, 0, stream>>>(x, h, (unsigned int*)xh0);

  k_prop96e<<<dim3(NN / 8), blk, 0, stream>>>((const uint2*)xh0, (uint2*)xh1,
                                              cursor, ell);
  k_prop96e<<<dim3(NN / 8), blk, 0, stream>>>((const uint2*)xh1, (uint2*)xh2,
                                              cursor, ell);
  k_rz<<<dim3((NN + GN - 1) / GN), blk, 0, stream>>>(xh0, xh1, xh2, wt_rz, br, bz, rh, zbb);
  k_prop64e<<<dim3(NN / 8), blk, 0, stream>>>((const unsigned int*)rh,
                                              (unsigned int*)rh1, cursor, ell);
  k_prop64e<<<dim3(NN / 8), blk, 0, stream>>>((const unsigned int*)rh1,
                                              (unsigned int*)rh2, cursor, ell);
  k_c<<<dim3((NN + GN - 1) / GN), blk, 0, stream>>>(xh0, rh, xh1, xh2, rh1, rh2,
                                                    wt_c, bc, zbb, out);
}